// Round 18
// baseline (54.752 us; speedup 1.0000x reference)
//
#include <hip/hip_runtime.h>
#include <hip/hip_bf16.h>

// B=8, C1=256, HW=4096 (N=32768), Ch=128, C2=256, E=4, K=2
// ws layout (u16) — identical to R11/R13/R16:
//   W1hi [kc=4][128][72] @0        (36864)
//   W1lo [kc=4][128][72] @36864    (36864)
//   Wec  [e=4][128][128] swz @73728  (65536)
//   W3c  [h=2][128][128] swz @139264 (32768)

typedef unsigned short u16;
typedef unsigned int   u32;
typedef __attribute__((ext_vector_type(8))) short short8;
typedef __attribute__((ext_vector_type(4))) float f32x4;

#define MFMA16 __builtin_amdgcn_mfma_f32_16x16x32_bf16

__device__ __forceinline__ float silu_f(float v) { return v / (1.0f + __expf(-v)); }
__device__ __forceinline__ u16 f2bf(float f) {
    u32 u = __float_as_uint(f);
    return (u16)((u + 0x7fff + ((u >> 16) & 1)) >> 16);
}
__device__ __forceinline__ float bf2f(u16 h) { return __uint_as_float(((u32)h) << 16); }
__device__ __forceinline__ u32 pkbf(float a, float b) {
    __hip_bfloat162 h2 = __float22bfloat162_rn(make_float2(a, b));
    u32 r; __builtin_memcpy(&r, &h2, 4); return r;
}
__device__ __forceinline__ int key3(int r) { return (r ^ (r >> 2)) & 7; }

__global__ void prep_weights(const float* __restrict__ W1,
                             const float* __restrict__ We,
                             const float* __restrict__ W3,
                             u16* __restrict__ ws)
{
    int idx = blockIdx.x * 256 + threadIdx.x;
    if (idx < 36864) {                       // W1 hi+lo, K-chunks of 64, stride 72
        int kc = idx / 9216, r = idx % 9216;
        int n = r / 72, j = r % 72;
        float v = (j < 64) ? W1[n * 256 + kc * 64 + j] : 0.0f;
        u16 h = f2bf(v);
        float lo = v - bf2f(h);
        ws[idx] = h;
        ws[36864 + idx] = f2bf(lo);
    } else if (idx < 102400) {               // We center taps, [e][128][128] swz
        int i = idx - 36864;
        int e = i >> 14, r = i & 16383;
        int o = r >> 7, rem = r & 127;
        int ps = rem >> 3, t = rem & 7;
        int gi = (ps & 8) | ((ps ^ key3(o)) & 7);
        int c = gi * 8 + t;
        ws[73728 + i] = f2bf(We[(size_t)(((e * 128 + o) * 128 + c) * 9) + 4]);
    } else if (idx < 135168) {               // W3, [h][128][128] swz
        int i = idx - 102400;
        int h = i >> 14, r = i & 16383;
        int o = r >> 7, rem = r & 127;
        int ps = rem >> 3, t = rem & 7;
        int gi = (ps & 8) | ((ps ^ key3(o)) & 7);
        int c = gi * 8 + t;
        ws[139264 + i] = f2bf(W3[(size_t)(h * 128 + o) * 128 + c]);
    }
}

// Linear DMA of a 32 KB chunk with 512 threads (2048 16B-units, 4/thread).
__device__ __forceinline__ void stage_chunk(const u16* __restrict__ g, u16* l, int tid) {
#pragma unroll
    for (int i = 0; i < 4; ++i)
        __builtin_amdgcn_global_load_lds(g + (size_t)(i * 512 + tid) * 8,
                                         l + (size_t)(i * 512 + (tid & 448)) * 8, 16, 0, 0);
}

// One block = 64 px, 512 threads (8 waves: wm=row-tile 0..3, wn=channel-half).
// R16 structure + A-fragment hoisting (no setprio anywhere).
__global__ __launch_bounds__(512, 4)
void fused_moe_mfma(const float* __restrict__ x,
                    const float* __restrict__ b1g,
                    const float* __restrict__ Wrg,
                    const float* __restrict__ brg,
                    const float* __restrict__ beg,
                    const float* __restrict__ b3g,
                    const u16* __restrict__ wbf,
                    float* __restrict__ out)
{
    __shared__ __align__(16) unsigned char smem[81920];
    // P1 (dead after P1):
    u16*   const sWhi = (u16*)(smem);             // [128][72] = 18432 B
    u16*   const sWlo = (u16*)(smem + 18432);
    u16*   const sAhi = (u16*)(smem + 36864);     // [64][72], quad-XOR-swizzled
    u16*   const sAlo = (u16*)(smem + 46080);     // ends 55296
    // P2/P3:
    u16*   const A2   = (u16*)(smem);             // [64][128] swz = 16384 B (A2/A3)
    u16*   const bufA = (u16*)(smem + 16384);     // 32768 B
    u16*   const bufB = (u16*)(smem + 49152);     // 32768 B
    float* const sLg  = (float*)(smem + 49152);   // [2][64][4] f32 (bufB head; barrier-protected)
    float* const sY   = (float*)(smem + 16384);   // [128][64] f32 swz (bufA region)

    const int tid = threadIdx.x;
    const int l  = tid & 63;
    const int w  = tid >> 6;        // 0..7
    const int wm = w & 3, wn = w >> 2;
    const int lr = l & 15;
    const int g  = l >> 4;
    const int mrow = 16 * wm + 4 * g;
    const int arow = 16 * wm + lr;
    const int ak3 = key3(arow);
    int oc[4], ok3[4];
#pragma unroll
    for (int f = 0; f < 4; ++f) { oc[f] = 64 * wn + 16 * f + lr; ok3[f] = key3(oc[f]); }

    const int n0  = blockIdx.x << 6;
    const float* xb = x   + ((size_t)(n0 >> 12) * 256) * 4096 + (n0 & 4095);
    float*       ob = out + ((size_t)(n0 >> 12) * 256) * 4096 + (n0 & 4095);

    // Hoisted uniform-ish loads: hidden under P1 (b1/Wr/br).
    float b1v[4], wrv[4][4], brv[4];
#pragma unroll
    for (int f = 0; f < 4; ++f) {
        int c = oc[f];
        b1v[f]    = b1g[c];
        wrv[0][f] = Wrg[c];       wrv[1][f] = Wrg[128 + c];
        wrv[2][f] = Wrg[256 + c]; wrv[3][f] = Wrg[384 + c];
    }
#pragma unroll
    for (int e = 0; e < 4; ++e) brv[e] = brg[e];

    // ============ P1: GEMM1, split-bf16 4-pass (bit-identical to R13) ============
    f32x4 acc1[4];
#pragma unroll
    for (int f = 0; f < 4; ++f) acc1[f] = (f32x4){0.f, 0.f, 0.f, 0.f};

    const int c2 = tid >> 4;        // channel-pair 0..31
    const int m4 = (tid & 15) << 2; // pixel row base

    // x(0) issued up-front (latency overlaps the hoisted loads above)
    float4 fa, fb;
    {
        const float* xa = xb + (size_t)(2 * c2) * 4096 + m4;
        fa = *(const float4*)xa;
        fb = *(const float4*)(xa + 4096);
    }

#pragma unroll 1
    for (int kc = 0; kc < 4; ++kc) {
        __syncthreads();            // BAR-A: frees A/W buffers
        // DMA W1 chunk kc (hi+lo, 1152 16B-units each)
#pragma unroll
        for (int i = 0; i < 3; ++i) {
            int idx = i * 512 + tid;
            if (idx < 1152) {
                int ub = i * 512 + (tid & 448);
                __builtin_amdgcn_global_load_lds(wbf + (size_t)kc * 9216 + (size_t)idx * 8,
                                                 sWhi + (size_t)ub * 8, 16, 0, 0);
                __builtin_amdgcn_global_load_lds(wbf + (size_t)(36864 + kc * 9216) + (size_t)idx * 8,
                                                 sWlo + (size_t)ub * 8, 16, 0, 0);
            }
        }
        // split conversion -> A hi/lo, quad-XOR-swizzled store
        {
            u32* H = (u32*)sAhi; u32* L = (u32*)sAlo;
            float fav[4] = {fa.x, fa.y, fa.z, fa.w};
            float fbv[4] = {fb.x, fb.y, fb.z, fb.w};
#pragma unroll
            for (int r = 0; r < 4; ++r) {
                int row = m4 + r;
                u32 hi = pkbf(fav[r], fbv[r]);
                float la = fav[r] - __uint_as_float(hi << 16);
                float lb = fbv[r] - __uint_as_float(hi & 0xffff0000u);
                int jj = c2 ^ (key3(row) << 2);
                H[row * 36 + jj] = hi; L[row * 36 + jj] = pkbf(la, lb);
            }
        }
        // prefetch x(kc+1): latency piggybacks on BAR-B's vmcnt(0) drain
        float4 na, nb;
        if (kc < 3) {
            const float* xn = xb + (size_t)((kc + 1) * 64 + 2 * c2) * 4096 + m4;
            na = *(const float4*)xn;
            nb = *(const float4*)(xn + 4096);
        }
        __syncthreads();            // BAR-B: drains DMA + A writes (+ x prefetch)
#pragma unroll
        for (int ks = 0; ks < 2; ++ks) {
            int jb = (ks * 16 + g * 4) ^ (ak3 << 2);   // swizzled u32 quad base
            short8 ah = *(const short8*)&sAhi[arow * 72 + jb * 2];
            short8 al = *(const short8*)&sAlo[arow * 72 + jb * 2];
#pragma unroll
            for (int f = 0; f < 4; ++f) {
                int bo = oc[f] * 72 + ks * 32 + g * 8;
                short8 bh = *(const short8*)&sWhi[bo];
                short8 bl = *(const short8*)&sWlo[bo];
                acc1[f] = MFMA16(ah, bh, acc1[f], 0, 0, 0);
                acc1[f] = MFMA16(al, bh, acc1[f], 0, 0, 0);
                acc1[f] = MFMA16(ah, bl, acc1[f], 0, 0, 0);
                acc1[f] = MFMA16(al, bl, acc1[f], 0, 0, 0);
            }
        }
        if (kc < 3) { fa = na; fb = nb; }
    }
    __syncthreads();                 // P1 readers done; bufA region free
    stage_chunk(wbf + 73728, bufA, tid);   // expert 0 flies under the epilogue

    // ============ epilogue: xin fp32; A2 swz; router partials via sLg ============
    float xin[4][4];
#pragma unroll
    for (int f = 0; f < 4; ++f) {
#pragma unroll
        for (int i = 0; i < 4; ++i) xin[f][i] = silu_f(acc1[f][i] + b1v[f]);
    }
#pragma unroll
    for (int f = 0; f < 4; ++f) {
        int c = oc[f], cg = c >> 3;
#pragma unroll
        for (int i = 0; i < 4; ++i) {
            int m = mrow + i;
            int ps = (cg & 8) | ((cg ^ key3(m)) & 7);
            A2[m * 128 + ps * 8 + (c & 7)] = f2bf(xin[f][i]);
        }
    }
    float lg[4][4];
#pragma unroll
    for (int e = 0; e < 4; ++e)
#pragma unroll
        for (int i = 0; i < 4; ++i) lg[e][i] = 0.f;
#pragma unroll
    for (int f = 0; f < 4; ++f) {
#pragma unroll
        for (int i = 0; i < 4; ++i) {
            float xv = xin[f][i];
            lg[0][i] += xv * wrv[0][f]; lg[1][i] += xv * wrv[1][f];
            lg[2][i] += xv * wrv[2][f]; lg[3][i] += xv * wrv[3][f];
        }
    }
#pragma unroll
    for (int d = 1; d < 16; d <<= 1)
#pragma unroll
        for (int e = 0; e < 4; ++e)
#pragma unroll
            for (int i = 0; i < 4; ++i)
                lg[e][i] += __shfl_xor(lg[e][i], d, 64);
    if (lr == 0) {
#pragma unroll
        for (int i = 0; i < 4; ++i)
#pragma unroll
            for (int e = 0; e < 4; ++e)
                sLg[(wn * 64 + mrow + i) * 4 + e] = lg[e][i];
    }
    __syncthreads();                 // sLg + A2 visible; e0 DMA drained

    float rw[4][4];
#pragma unroll
    for (int i = 0; i < 4; ++i) {
        int m = mrow + i;
        float le0 = sLg[m * 4 + 0] + sLg[(64 + m) * 4 + 0] + brv[0];
        float le1 = sLg[m * 4 + 1] + sLg[(64 + m) * 4 + 1] + brv[1];
        float le2 = sLg[m * 4 + 2] + sLg[(64 + m) * 4 + 2] + brv[2];
        float le3 = sLg[m * 4 + 3] + sLg[(64 + m) * 4 + 3] + brv[3];
        int c0 = (le1 > le0) + (le2 > le0) + (le3 > le0);
        int c1 = (le0 >= le1) + (le2 > le1) + (le3 > le1);
        int c2r = (le0 >= le2) + (le1 >= le2) + (le3 > le2);
        int c3 = (le0 >= le3) + (le1 >= le3) + (le2 >= le3);
        float m0 = fmaxf(fmaxf(le0, le1), fmaxf(le2, le3));
        float p0 = (c0 < 2) ? __expf(le0 - m0) : 0.f;
        float p1 = (c1 < 2) ? __expf(le1 - m0) : 0.f;
        float p2 = (c2r < 2) ? __expf(le2 - m0) : 0.f;
        float p3 = (c3 < 2) ? __expf(le3 - m0) : 0.f;
        float inv = 1.0f / (p0 + p1 + p2 + p3);
        rw[0][i] = p0 * inv; rw[1][i] = p1 * inv;
        rw[2][i] = p2 * inv; rw[3][i] = p3 * inv;
    }
    // Hoist A2 fragments ONCE (invariant across the 4 experts).
    short8 af[4];
#pragma unroll
    for (int ks = 0; ks < 4; ++ks) {
        int gi = ks * 4 + g;
        int psA = (gi & 8) | ((gi ^ ak3) & 7);
        af[ks] = *(const short8*)&A2[arow * 128 + psA * 8];
    }
    __syncthreads();                 // ALL sLg reads done -> bufB may receive DMA
    stage_chunk(wbf + 73728 + 16384, bufB, tid);   // expert 1

    // ============ P2: experts (chain: chunk e+2 staged as buffer frees) ============
    f32x4 macc[4];
#pragma unroll
    for (int f = 0; f < 4; ++f) macc[f] = (f32x4){0.f, 0.f, 0.f, 0.f};

#pragma unroll 1
    for (int e = 0; e < 4; ++e) {
        // bias prefetch: flight spans the MFMA cluster
        float bevc[4];
#pragma unroll
        for (int f = 0; f < 4; ++f) bevc[f] = beg[e * 128 + oc[f]];
        const u16* Wb = (e & 1) ? bufB : bufA;
        f32x4 acce[4];
#pragma unroll
        for (int f = 0; f < 4; ++f) acce[f] = (f32x4){0.f, 0.f, 0.f, 0.f};
#pragma unroll
        for (int ks = 0; ks < 4; ++ks) {
#pragma unroll
            for (int f = 0; f < 4; ++f) {
                int gi = ks * 4 + g;
                int psB = (gi & 8) | ((gi ^ ok3[f]) & 7);
                short8 bb = *(const short8*)&Wb[oc[f] * 128 + psB * 8];
                acce[f] = MFMA16(af[ks], bb, acce[f], 0, 0, 0);
            }
        }
#pragma unroll
        for (int f = 0; f < 4; ++f) {
#pragma unroll
            for (int i = 0; i < 4; ++i)
                macc[f][i] += rw[e][i] * silu_f(acce[f][i] + bevc[f]);
        }
        __syncthreads();             // Wb readers done; drains chunk e+1
        if (e < 2)       stage_chunk(wbf + 73728 + (e + 2) * 16384, (e & 1) ? bufB : bufA, tid);
        else if (e == 2) stage_chunk(wbf + 139264, bufA, tid);   // W3 h0
    }

    // moe -> A3 (A2 region; all A2 readers passed the e=3 barrier)
#pragma unroll
    for (int f = 0; f < 4; ++f) {
        int c = oc[f], cg = c >> 3;
#pragma unroll
        for (int i = 0; i < 4; ++i) {
            int m = mrow + i;
            int ps = (cg & 8) | ((cg ^ key3(m)) & 7);
            A2[m * 128 + ps * 8 + (c & 7)] = f2bf(macc[f][i]);
        }
    }
    __syncthreads();                 // A3 visible; drains W3 h0
    stage_chunk(wbf + 139264 + 16384, bufB, tid);   // W3 h1
    // Hoist A3 fragments ONCE (invariant across the 2 halves).
    short8 af3[4];
#pragma unroll
    for (int ks = 0; ks < 4; ++ks) {
        int gi = ks * 4 + g;
        int psA = (gi & 8) | ((gi ^ ak3) & 7);
        af3[ks] = *(const short8*)&A2[arow * 128 + psA * 8];
    }

    // ============ P3: GEMM3 + residual ============
#pragma unroll 1
    for (int h = 0; h < 2; ++h) {
        const u16* Wb = h ? bufB : bufA;
        // prefetch residuals + b3 for this half: drained at the post-MFMA barrier
        float4 rres[4];
#pragma unroll
        for (int q = 0; q < 4; ++q) {
            int idx = q * 512 + tid;
            int o = idx >> 4, mq = idx & 15;
            rres[q] = *(const float4*)&xb[(size_t)(h * 128 + o) * 4096 + (mq << 2)];
        }
        float b3c[4];
#pragma unroll
        for (int f = 0; f < 4; ++f) b3c[f] = b3g[h * 128 + oc[f]];

        f32x4 acc3[4];
#pragma unroll
        for (int f = 0; f < 4; ++f) acc3[f] = (f32x4){0.f, 0.f, 0.f, 0.f};
#pragma unroll
        for (int ks = 0; ks < 4; ++ks) {
#pragma unroll
            for (int f = 0; f < 4; ++f) {
                int gi = ks * 4 + g;
                int psB = (gi & 8) | ((gi ^ ok3[f]) & 7);
                short8 bb = *(const short8*)&Wb[oc[f] * 128 + psB * 8];
                acc3[f] = MFMA16(af3[ks], bb, acc3[f], 0, 0, 0);
            }
        }
        __syncthreads();             // h=0: frees bufA (sY overlays), drains W3 h1 (+prefetches)
        int mg = mrow >> 2;          // 4*wm + g, 0..15
#pragma unroll
        for (int f = 0; f < 4; ++f) {
            int o = oc[f];
            float4 v;
            v.x = silu_f(acc3[f][0] + b3c[f]);
            v.y = silu_f(acc3[f][1] + b3c[f]);
            v.z = silu_f(acc3[f][2] + b3c[f]);
            v.w = silu_f(acc3[f][3] + b3c[f]);
            *(float4*)&sY[o * 64 + ((mg ^ ok3[f]) << 2)] = v;
        }
        __syncthreads();
#pragma unroll
        for (int q = 0; q < 4; ++q) {    // coalesced residual-add + store
            int idx = q * 512 + tid;
            int o = idx >> 4, mq = idx & 15;
            int og = h * 128 + o;
            float4 vy = *(const float4*)&sY[o * 64 + ((mq ^ key3(o)) << 2)];
            size_t goff = (size_t)og * 4096 + (mq << 2);
            vy.x += rres[q].x; vy.y += rres[q].y;
            vy.z += rres[q].z; vy.w += rres[q].w;
            *(float4*)&ob[goff] = vy;
        }
        if (h == 0) __syncthreads(); // sY readers done before h=1 overwrites
    }
}

extern "C" void kernel_launch(void* const* d_in, const int* in_sizes, int n_in,
                              void* d_out, int out_size, void* d_ws, size_t ws_size,
                              hipStream_t stream)
{
    const float* x  = (const float*)d_in[0];
    const float* W1 = (const float*)d_in[1];
    const float* b1 = (const float*)d_in[2];
    const float* Wr = (const float*)d_in[3];
    const float* br = (const float*)d_in[4];
    const float* We = (const float*)d_in[5];
    const float* be = (const float*)d_in[6];
    const float* W3 = (const float*)d_in[7];
    const float* b3 = (const float*)d_in[8];
    float* outp = (float*)d_out;
    u16* wbf = (u16*)d_ws;

    hipLaunchKernelGGL(prep_weights, dim3(528), dim3(256), 0, stream,
                       W1, We, W3, wbf);
    hipLaunchKernelGGL(fused_moe_mfma, dim3(512), dim3(512), 0, stream,
                       x, b1, Wr, br, be, b3, wbf, outp);
}

// Round 19
// 49.995 us; speedup vs baseline: 1.0952x; 1.0952x over previous
//
#include <hip/hip_runtime.h>
#include <hip/hip_bf16.h>

// B=8, C1=256, HW=4096 (N=32768), Ch=128, C2=256, E=4, K=2
// ws layout (u16) — identical to R11/R13/R16:
//   W1hi [kc=4][128][72] @0        (36864)
//   W1lo [kc=4][128][72] @36864    (36864)
//   Wec  [e=4][128][128] swz @73728  (65536)
//   W3c  [h=2][128][128] swz @139264 (32768)

typedef unsigned short u16;
typedef unsigned int   u32;
typedef __attribute__((ext_vector_type(8))) short short8;
typedef __attribute__((ext_vector_type(4))) float f32x4;

#define MFMA16 __builtin_amdgcn_mfma_f32_16x16x32_bf16

__device__ __forceinline__ float silu_f(float v) { return v / (1.0f + __expf(-v)); }
__device__ __forceinline__ u16 f2bf(float f) {
    u32 u = __float_as_uint(f);
    return (u16)((u + 0x7fff + ((u >> 16) & 1)) >> 16);
}
__device__ __forceinline__ float bf2f(u16 h) { return __uint_as_float(((u32)h) << 16); }
__device__ __forceinline__ u32 pkbf(float a, float b) {
    __hip_bfloat162 h2 = __float22bfloat162_rn(make_float2(a, b));
    u32 r; __builtin_memcpy(&r, &h2, 4); return r;
}
__device__ __forceinline__ int key3(int r) { return (r ^ (r >> 2)) & 7; }

__global__ void prep_weights(const float* __restrict__ W1,
                             const float* __restrict__ We,
                             const float* __restrict__ W3,
                             u16* __restrict__ ws)
{
    int idx = blockIdx.x * 256 + threadIdx.x;
    if (idx < 36864) {                       // W1 hi+lo, K-chunks of 64, stride 72
        int kc = idx / 9216, r = idx % 9216;
        int n = r / 72, j = r % 72;
        float v = (j < 64) ? W1[n * 256 + kc * 64 + j] : 0.0f;
        u16 h = f2bf(v);
        float lo = v - bf2f(h);
        ws[idx] = h;
        ws[36864 + idx] = f2bf(lo);
    } else if (idx < 102400) {               // We center taps, [e][128][128] swz
        int i = idx - 36864;
        int e = i >> 14, r = i & 16383;
        int o = r >> 7, rem = r & 127;
        int ps = rem >> 3, t = rem & 7;
        int gi = (ps & 8) | ((ps ^ key3(o)) & 7);
        int c = gi * 8 + t;
        ws[73728 + i] = f2bf(We[(size_t)(((e * 128 + o) * 128 + c) * 9) + 4]);
    } else if (idx < 135168) {               // W3, [h][128][128] swz
        int i = idx - 102400;
        int h = i >> 14, r = i & 16383;
        int o = r >> 7, rem = r & 127;
        int ps = rem >> 3, t = rem & 7;
        int gi = (ps & 8) | ((ps ^ key3(o)) & 7);
        int c = gi * 8 + t;
        ws[139264 + i] = f2bf(W3[(size_t)(h * 128 + o) * 128 + c]);
    }
}

// Linear DMA of a 32 KB chunk with 512 threads (2048 16B-units, 4/thread).
__device__ __forceinline__ void stage_chunk(const u16* __restrict__ g, u16* l, int tid) {
#pragma unroll
    for (int i = 0; i < 4; ++i)
        __builtin_amdgcn_global_load_lds(g + (size_t)(i * 512 + tid) * 8,
                                         l + (size_t)(i * 512 + (tid & 448)) * 8, 16, 0, 0);
}

// One block = 64 px, 512 threads (8 waves: wm=row-tile 0..3, wn=channel-half).
// R16 structure (verified best): full-drain barriers only, DMA chaining,
// load-piggybacking on barrier drains. No A-frag hoist (spills), no setprio.
__global__ __launch_bounds__(512, 4)
void fused_moe_mfma(const float* __restrict__ x,
                    const float* __restrict__ b1g,
                    const float* __restrict__ Wrg,
                    const float* __restrict__ brg,
                    const float* __restrict__ beg,
                    const float* __restrict__ b3g,
                    const u16* __restrict__ wbf,
                    float* __restrict__ out)
{
    __shared__ __align__(16) unsigned char smem[81920];
    // P1 (dead after P1):
    u16*   const sWhi = (u16*)(smem);             // [128][72] = 18432 B
    u16*   const sWlo = (u16*)(smem + 18432);
    u16*   const sAhi = (u16*)(smem + 36864);     // [64][72], quad-XOR-swizzled
    u16*   const sAlo = (u16*)(smem + 46080);     // ends 55296
    // P2/P3:
    u16*   const A2   = (u16*)(smem);             // [64][128] swz = 16384 B (A2/A3)
    u16*   const bufA = (u16*)(smem + 16384);     // 32768 B
    u16*   const bufB = (u16*)(smem + 49152);     // 32768 B
    float* const sLg  = (float*)(smem + 49152);   // [2][64][4] f32 (bufB head; barrier-protected)
    float* const sY   = (float*)(smem + 16384);   // [128][64] f32 swz (bufA region)

    const int tid = threadIdx.x;
    const int l  = tid & 63;
    const int w  = tid >> 6;        // 0..7
    const int wm = w & 3, wn = w >> 2;
    const int lr = l & 15;
    const int g  = l >> 4;
    const int mrow = 16 * wm + 4 * g;
    const int arow = 16 * wm + lr;
    const int ak3 = key3(arow);
    int oc[4], ok3[4];
#pragma unroll
    for (int f = 0; f < 4; ++f) { oc[f] = 64 * wn + 16 * f + lr; ok3[f] = key3(oc[f]); }

    const int n0  = blockIdx.x << 6;
    const float* xb = x   + ((size_t)(n0 >> 12) * 256) * 4096 + (n0 & 4095);
    float*       ob = out + ((size_t)(n0 >> 12) * 256) * 4096 + (n0 & 4095);

    // Hoisted uniform-ish loads: hidden under P1 (b1/Wr/br).
    float b1v[4], wrv[4][4], brv[4];
#pragma unroll
    for (int f = 0; f < 4; ++f) {
        int c = oc[f];
        b1v[f]    = b1g[c];
        wrv[0][f] = Wrg[c];       wrv[1][f] = Wrg[128 + c];
        wrv[2][f] = Wrg[256 + c]; wrv[3][f] = Wrg[384 + c];
    }
#pragma unroll
    for (int e = 0; e < 4; ++e) brv[e] = brg[e];

    // ============ P1: GEMM1, split-bf16 4-pass (bit-identical to R13) ============
    f32x4 acc1[4];
#pragma unroll
    for (int f = 0; f < 4; ++f) acc1[f] = (f32x4){0.f, 0.f, 0.f, 0.f};

    const int c2 = tid >> 4;        // channel-pair 0..31
    const int m4 = (tid & 15) << 2; // pixel row base

    // x(0) issued up-front (latency overlaps the hoisted loads above)
    float4 fa, fb;
    {
        const float* xa = xb + (size_t)(2 * c2) * 4096 + m4;
        fa = *(const float4*)xa;
        fb = *(const float4*)(xa + 4096);
    }

#pragma unroll 1
    for (int kc = 0; kc < 4; ++kc) {
        __syncthreads();            // BAR-A: frees A/W buffers
        // DMA W1 chunk kc (hi+lo, 1152 16B-units each)
#pragma unroll
        for (int i = 0; i < 3; ++i) {
            int idx = i * 512 + tid;
            if (idx < 1152) {
                int ub = i * 512 + (tid & 448);
                __builtin_amdgcn_global_load_lds(wbf + (size_t)kc * 9216 + (size_t)idx * 8,
                                                 sWhi + (size_t)ub * 8, 16, 0, 0);
                __builtin_amdgcn_global_load_lds(wbf + (size_t)(36864 + kc * 9216) + (size_t)idx * 8,
                                                 sWlo + (size_t)ub * 8, 16, 0, 0);
            }
        }
        // split conversion -> A hi/lo, quad-XOR-swizzled store
        {
            u32* H = (u32*)sAhi; u32* L = (u32*)sAlo;
            float fav[4] = {fa.x, fa.y, fa.z, fa.w};
            float fbv[4] = {fb.x, fb.y, fb.z, fb.w};
#pragma unroll
            for (int r = 0; r < 4; ++r) {
                int row = m4 + r;
                u32 hi = pkbf(fav[r], fbv[r]);
                float la = fav[r] - __uint_as_float(hi << 16);
                float lb = fbv[r] - __uint_as_float(hi & 0xffff0000u);
                int jj = c2 ^ (key3(row) << 2);
                H[row * 36 + jj] = hi; L[row * 36 + jj] = pkbf(la, lb);
            }
        }
        // prefetch x(kc+1): latency piggybacks on BAR-B's vmcnt(0) drain
        float4 na, nb;
        if (kc < 3) {
            const float* xn = xb + (size_t)((kc + 1) * 64 + 2 * c2) * 4096 + m4;
            na = *(const float4*)xn;
            nb = *(const float4*)(xn + 4096);
        }
        __syncthreads();            // BAR-B: drains DMA + A writes (+ x prefetch)
#pragma unroll
        for (int ks = 0; ks < 2; ++ks) {
            int jb = (ks * 16 + g * 4) ^ (ak3 << 2);   // swizzled u32 quad base
            short8 ah = *(const short8*)&sAhi[arow * 72 + jb * 2];
            short8 al = *(const short8*)&sAlo[arow * 72 + jb * 2];
#pragma unroll
            for (int f = 0; f < 4; ++f) {
                int bo = oc[f] * 72 + ks * 32 + g * 8;
                short8 bh = *(const short8*)&sWhi[bo];
                short8 bl = *(const short8*)&sWlo[bo];
                acc1[f] = MFMA16(ah, bh, acc1[f], 0, 0, 0);
                acc1[f] = MFMA16(al, bh, acc1[f], 0, 0, 0);
                acc1[f] = MFMA16(ah, bl, acc1[f], 0, 0, 0);
                acc1[f] = MFMA16(al, bl, acc1[f], 0, 0, 0);
            }
        }
        if (kc < 3) { fa = na; fb = nb; }
    }
    __syncthreads();                 // P1 readers done; bufA region free
    stage_chunk(wbf + 73728, bufA, tid);   // expert 0 flies under the epilogue

    // ============ epilogue: xin fp32; A2 swz; router partials via sLg ============
    float xin[4][4];
#pragma unroll
    for (int f = 0; f < 4; ++f) {
#pragma unroll
        for (int i = 0; i < 4; ++i) xin[f][i] = silu_f(acc1[f][i] + b1v[f]);
    }
#pragma unroll
    for (int f = 0; f < 4; ++f) {
        int c = oc[f], cg = c >> 3;
#pragma unroll
        for (int i = 0; i < 4; ++i) {
            int m = mrow + i;
            int ps = (cg & 8) | ((cg ^ key3(m)) & 7);
            A2[m * 128 + ps * 8 + (c & 7)] = f2bf(xin[f][i]);
        }
    }
    float lg[4][4];
#pragma unroll
    for (int e = 0; e < 4; ++e)
#pragma unroll
        for (int i = 0; i < 4; ++i) lg[e][i] = 0.f;
#pragma unroll
    for (int f = 0; f < 4; ++f) {
#pragma unroll
        for (int i = 0; i < 4; ++i) {
            float xv = xin[f][i];
            lg[0][i] += xv * wrv[0][f]; lg[1][i] += xv * wrv[1][f];
            lg[2][i] += xv * wrv[2][f]; lg[3][i] += xv * wrv[3][f];
        }
    }
#pragma unroll
    for (int d = 1; d < 16; d <<= 1)
#pragma unroll
        for (int e = 0; e < 4; ++e)
#pragma unroll
            for (int i = 0; i < 4; ++i)
                lg[e][i] += __shfl_xor(lg[e][i], d, 64);
    if (lr == 0) {
#pragma unroll
        for (int i = 0; i < 4; ++i)
#pragma unroll
            for (int e = 0; e < 4; ++e)
                sLg[(wn * 64 + mrow + i) * 4 + e] = lg[e][i];
    }
    __syncthreads();                 // sLg + A2 visible; e0 DMA drained

    float rw[4][4];
#pragma unroll
    for (int i = 0; i < 4; ++i) {
        int m = mrow + i;
        float le0 = sLg[m * 4 + 0] + sLg[(64 + m) * 4 + 0] + brv[0];
        float le1 = sLg[m * 4 + 1] + sLg[(64 + m) * 4 + 1] + brv[1];
        float le2 = sLg[m * 4 + 2] + sLg[(64 + m) * 4 + 2] + brv[2];
        float le3 = sLg[m * 4 + 3] + sLg[(64 + m) * 4 + 3] + brv[3];
        int c0 = (le1 > le0) + (le2 > le0) + (le3 > le0);
        int c1 = (le0 >= le1) + (le2 > le1) + (le3 > le1);
        int c2r = (le0 >= le2) + (le1 >= le2) + (le3 > le2);
        int c3 = (le0 >= le3) + (le1 >= le3) + (le2 >= le3);
        float m0 = fmaxf(fmaxf(le0, le1), fmaxf(le2, le3));
        float p0 = (c0 < 2) ? __expf(le0 - m0) : 0.f;
        float p1 = (c1 < 2) ? __expf(le1 - m0) : 0.f;
        float p2 = (c2r < 2) ? __expf(le2 - m0) : 0.f;
        float p3 = (c3 < 2) ? __expf(le3 - m0) : 0.f;
        float inv = 1.0f / (p0 + p1 + p2 + p3);
        rw[0][i] = p0 * inv; rw[1][i] = p1 * inv;
        rw[2][i] = p2 * inv; rw[3][i] = p3 * inv;
    }
    __syncthreads();                 // ALL sLg reads done -> bufB may receive DMA
    stage_chunk(wbf + 73728 + 16384, bufB, tid);   // expert 1

    // ============ P2: experts (chain: chunk e+2 staged as buffer frees) ============
    f32x4 macc[4];
#pragma unroll
    for (int f = 0; f < 4; ++f) macc[f] = (f32x4){0.f, 0.f, 0.f, 0.f};

#pragma unroll 1
    for (int e = 0; e < 4; ++e) {
        // bias prefetch: flight spans the MFMA cluster
        float bevc[4];
#pragma unroll
        for (int f = 0; f < 4; ++f) bevc[f] = beg[e * 128 + oc[f]];
        const u16* Wb = (e & 1) ? bufB : bufA;
        f32x4 acce[4];
#pragma unroll
        for (int f = 0; f < 4; ++f) acce[f] = (f32x4){0.f, 0.f, 0.f, 0.f};
#pragma unroll
        for (int ks = 0; ks < 4; ++ks) {
            int gi = ks * 4 + g;
            int psA = (gi & 8) | ((gi ^ ak3) & 7);
            short8 a = *(const short8*)&A2[arow * 128 + psA * 8];
#pragma unroll
            for (int f = 0; f < 4; ++f) {
                int psB = (gi & 8) | ((gi ^ ok3[f]) & 7);
                short8 bb = *(const short8*)&Wb[oc[f] * 128 + psB * 8];
                acce[f] = MFMA16(a, bb, acce[f], 0, 0, 0);
            }
        }
#pragma unroll
        for (int f = 0; f < 4; ++f) {
#pragma unroll
            for (int i = 0; i < 4; ++i)
                macc[f][i] += rw[e][i] * silu_f(acce[f][i] + bevc[f]);
        }
        __syncthreads();             // Wb readers done; drains chunk e+1
        if (e < 2)       stage_chunk(wbf + 73728 + (e + 2) * 16384, (e & 1) ? bufB : bufA, tid);
        else if (e == 2) stage_chunk(wbf + 139264, bufA, tid);   // W3 h0
    }

    // moe -> A3 (A2 region; all A2 readers passed the e=3 barrier)
#pragma unroll
    for (int f = 0; f < 4; ++f) {
        int c = oc[f], cg = c >> 3;
#pragma unroll
        for (int i = 0; i < 4; ++i) {
            int m = mrow + i;
            int ps = (cg & 8) | ((cg ^ key3(m)) & 7);
            A2[m * 128 + ps * 8 + (c & 7)] = f2bf(macc[f][i]);
        }
    }
    __syncthreads();                 // A3 visible; drains W3 h0
    stage_chunk(wbf + 139264 + 16384, bufB, tid);   // W3 h1

    // ============ P3: GEMM3 + residual ============
#pragma unroll 1
    for (int h = 0; h < 2; ++h) {
        const u16* Wb = h ? bufB : bufA;
        // prefetch residuals + b3 for this half: drained at the post-MFMA barrier
        float4 rres[4];
#pragma unroll
        for (int q = 0; q < 4; ++q) {
            int idx = q * 512 + tid;
            int o = idx >> 4, mq = idx & 15;
            rres[q] = *(const float4*)&xb[(size_t)(h * 128 + o) * 4096 + (mq << 2)];
        }
        float b3c[4];
#pragma unroll
        for (int f = 0; f < 4; ++f) b3c[f] = b3g[h * 128 + oc[f]];

        f32x4 acc3[4];
#pragma unroll
        for (int f = 0; f < 4; ++f) acc3[f] = (f32x4){0.f, 0.f, 0.f, 0.f};
#pragma unroll
        for (int ks = 0; ks < 4; ++ks) {
            int gi = ks * 4 + g;
            int psA = (gi & 8) | ((gi ^ ak3) & 7);
            short8 a = *(const short8*)&A2[arow * 128 + psA * 8];
#pragma unroll
            for (int f = 0; f < 4; ++f) {
                int psB = (gi & 8) | ((gi ^ ok3[f]) & 7);
                short8 bb = *(const short8*)&Wb[oc[f] * 128 + psB * 8];
                acc3[f] = MFMA16(a, bb, acc3[f], 0, 0, 0);
            }
        }
        __syncthreads();             // h=0: frees bufA (sY overlays), drains W3 h1 (+prefetches)
        int mg = mrow >> 2;          // 4*wm + g, 0..15
#pragma unroll
        for (int f = 0; f < 4; ++f) {
            int o = oc[f];
            float4 v;
            v.x = silu_f(acc3[f][0] + b3c[f]);
            v.y = silu_f(acc3[f][1] + b3c[f]);
            v.z = silu_f(acc3[f][2] + b3c[f]);
            v.w = silu_f(acc3[f][3] + b3c[f]);
            *(float4*)&sY[o * 64 + ((mg ^ ok3[f]) << 2)] = v;
        }
        __syncthreads();
#pragma unroll
        for (int q = 0; q < 4; ++q) {    // coalesced residual-add + store
            int idx = q * 512 + tid;
            int o = idx >> 4, mq = idx & 15;
            int og = h * 128 + o;
            float4 vy = *(const float4*)&sY[o * 64 + ((mq ^ key3(o)) << 2)];
            size_t goff = (size_t)og * 4096 + (mq << 2);
            vy.x += rres[q].x; vy.y += rres[q].y;
            vy.z += rres[q].z; vy.w += rres[q].w;
            *(float4*)&ob[goff] = vy;
        }
        if (h == 0) __syncthreads(); // sY readers done before h=1 overwrites
    }
}

extern "C" void kernel_launch(void* const* d_in, const int* in_sizes, int n_in,
                              void* d_out, int out_size, void* d_ws, size_t ws_size,
                              hipStream_t stream)
{
    const float* x  = (const float*)d_in[0];
    const float* W1 = (const float*)d_in[1];
    const float* b1 = (const float*)d_in[2];
    const float* Wr = (const float*)d_in[3];
    const float* br = (const float*)d_in[4];
    const float* We = (const float*)d_in[5];
    const float* be = (const float*)d_in[6];
    const float* W3 = (const float*)d_in[7];
    const float* b3 = (const float*)d_in[8];
    float* outp = (float*)d_out;
    u16* wbf = (u16*)d_ws;

    hipLaunchKernelGGL(prep_weights, dim3(528), dim3(256), 0, stream,
                       W1, We, W3, wbf);
    hipLaunchKernelGGL(fused_moe_mfma, dim3(512), dim3(512), 0, stream,
                       x, b1, Wr, br, be, b3, wbf, outp);
}